// Round 14
// baseline (1592.745 us; speedup 1.0000x reference)
//
#include <hip/hip_runtime.h>
#include <hip/hip_bf16.h>
#include <math.h>

// ---------------------------------------------------------------------------
// GPT forward, round 14: round-12 state (swz=1 everywhere) + fc2 moved to the
// 256x256 8-phase counted-vmcnt GEMM with split-K=8 (grid 32x8z = 256 blocks
// = 1/CU, nk=8), bf16 partials, fredln<8> reduce. lm_head path unchanged.
// ---------------------------------------------------------------------------

#define DEV_INLINE __device__ __forceinline__

typedef float  f32x4  __attribute__((ext_vector_type(4)));
typedef __bf16 bf16x8 __attribute__((ext_vector_type(8)));
typedef short  s16x4  __attribute__((ext_vector_type(4)));
typedef short  s16x8  __attribute__((ext_vector_type(8)));
typedef unsigned int u32x4 __attribute__((ext_vector_type(4)));

#define BBATCH 2
#define TSEQ   1024
#define DMODEL 1024
#define NHEAD  16
#define HDIM   64
#define NLAYER 8
#define NVOCAB 32000
#define MTOK   (BBATCH*TSEQ)   // 2048

DEV_INLINE short f2bf(float f) {
    __bf16 h = (__bf16)f;
    union { __bf16 h; short s; } u; u.h = h; return u.s;
}
DEV_INLINE float bf2f(short s) {
    union { unsigned u; float f; } x; x.u = ((unsigned)(unsigned short)s) << 16;
    return x.f;
}

typedef const __attribute__((address_space(1))) unsigned int* gas_t;
typedef __attribute__((address_space(3))) unsigned int* las_t;
DEV_INLINE void llds16(const void* g, void* l) {
    __builtin_amdgcn_global_load_lds((gas_t)g, (las_t)l, 16, 0, 0);
}

#define BAR()  asm volatile("s_barrier" ::: "memory")
#define VMW4() asm volatile("s_waitcnt vmcnt(4)" ::: "memory")
#define VMW2() asm volatile("s_waitcnt vmcnt(2)" ::: "memory")
#define VMW0() asm volatile("s_waitcnt vmcnt(0)" ::: "memory")

DEV_INLINE float block_sum(float v) {
    __shared__ float sb[4];
    #pragma unroll
    for (int o = 32; o > 0; o >>= 1) v += __shfl_down(v, o, 64);
    if ((threadIdx.x & 63) == 0) sb[threadIdx.x >> 6] = v;
    __syncthreads();
    float r = sb[0] + sb[1] + sb[2] + sb[3];
    __syncthreads();
    return r;
}

// ---------------------------------------------------------------------------
// Flash attention (round-8 structure): grid (8 q-blocks, 32 bh), 256 threads;
// KV tiles 128; reg-prefetch of next K/V tile.
// ---------------------------------------------------------------------------
__global__ __launch_bounds__(256) void flash_k(
    const short* __restrict__ qkv, const short* __restrict__ Vt,
    short* __restrict__ O)
{
    const int qb = blockIdx.x;          // 0..7
    const int z  = blockIdx.y;          // 0..31
    const int zb = z >> 4, zh = z & 15;

    __shared__ short Qs[128 * 64];
    __shared__ short KP[128 * 136];
    __shared__ short Vs[64 * 128];

    const int tid  = threadIdx.x;
    const int w    = tid >> 6, lane = tid & 63;
    const int lr   = lane & 15, kg = lane >> 4;

    const long long qbase = (long long)zb * TSEQ * 3072;
    const short* Qg = qkv + qbase + zh * HDIM;
    const short* Kg = qkv + qbase + DMODEL + zh * HDIM;
    const short* Vg = Vt + (long long)z * (HDIM * TSEQ);

    const int sr   = tid >> 3, pc = tid & 7;
    const int lc   = pc ^ (sr & 7);
    const int sr16 = tid >> 4, pc16 = tid & 15;

    {
        const short* qp = Qg + (long long)(qb * 128 + sr) * 3072 + lc * 8;
        const short* kp = Kg + (long long)(0 + sr) * 3072 + lc * 8;
        #pragma unroll
        for (int it = 0; it < 4; ++it) {
            llds16(qp + (long long)it * 32 * 3072, Qs + tid * 8 + it * 2048);
            llds16(kp + (long long)it * 32 * 3072, KP + tid * 8 + it * 2048);
        }
        #pragma unroll
        for (int it = 0; it < 4; ++it) {
            const int r = it * 16 + sr16;
            const int lc2 = pc16 ^ (r & 7);
            llds16(Vg + (long long)r * TSEQ + 0 + lc2 * 8, Vs + tid * 8 + it * 2048);
        }
    }
    __syncthreads();
    bf16x8 afq[2][2];
    #pragma unroll
    for (int s = 0; s < 2; ++s)
        #pragma unroll
        for (int i = 0; i < 2; ++i) {
            const int r = w * 32 + i * 16 + lr;
            afq[s][i] = *(const bf16x8*)&Qs[r * 64 + (((s * 4 + kg) ^ (r & 7)) << 3)];
        }

    f32x4 aco[2][4] = {};
    float m_[2][4], l_[2][4];
    #pragma unroll
    for (int i = 0; i < 2; ++i)
        #pragma unroll
        for (int p = 0; p < 4; ++p) { m_[i][p] = -1e30f; l_[i][p] = 0.f; }

    const int nt = qb + 1;
    for (int t = 0; t < nt; ++t) {
        u32x4 kpre[4], vpre[4];
        const bool nx = (t + 1 < nt);
        if (nx) {
            const int kn = (t + 1) * 128;
            #pragma unroll
            for (int it = 0; it < 4; ++it)
                kpre[it] = *(const u32x4*)(Kg + (long long)(kn + sr + it * 32) * 3072 + lc * 8);
            #pragma unroll
            for (int it = 0; it < 4; ++it) {
                const int r = it * 16 + sr16;
                const int lc2 = pc16 ^ (r & 7);
                vpre[it] = *(const u32x4*)(Vg + (long long)r * TSEQ + kn + lc2 * 8);
            }
            __builtin_amdgcn_sched_barrier(0);
        }

        f32x4 acs[2][8] = {};
        #pragma unroll
        for (int s = 0; s < 2; ++s)
            #pragma unroll
            for (int j = 0; j < 8; ++j) {
                const int rk = j * 16 + lr;
                bf16x8 bk = *(const bf16x8*)&KP[rk * 64 + (((s * 4 + kg) ^ (rk & 7)) << 3)];
                #pragma unroll
                for (int i = 0; i < 2; ++i)
                    acs[i][j] = __builtin_amdgcn_mfma_f32_16x16x32_bf16(
                        afq[s][i], bk, acs[i][j], 0, 0, 0);
            }

        #pragma unroll
        for (int i = 0; i < 2; ++i)
            #pragma unroll
            for (int j = 0; j < 8; ++j)
                #pragma unroll
                for (int p = 0; p < 4; ++p) {
                    float v = acs[i][j][p] * 0.125f;
                    if (t == qb && (j * 16 + lr) > (w * 32 + i * 16 + kg * 4 + p))
                        v = -1e30f;
                    acs[i][j][p] = v;
                }

        float sc[2][4];
        #pragma unroll
        for (int i = 0; i < 2; ++i)
            #pragma unroll
            for (int p = 0; p < 4; ++p) {
                float r = acs[i][0][p];
                #pragma unroll
                for (int j = 1; j < 8; ++j) r = fmaxf(r, acs[i][j][p]);
                r = fmaxf(r, __shfl_xor(r, 1, 64));
                r = fmaxf(r, __shfl_xor(r, 2, 64));
                r = fmaxf(r, __shfl_xor(r, 4, 64));
                r = fmaxf(r, __shfl_xor(r, 8, 64));
                const float mn = fmaxf(m_[i][p], r);
                sc[i][p] = __expf(m_[i][p] - mn);
                m_[i][p] = mn;
            }
        #pragma unroll
        for (int i = 0; i < 2; ++i)
            #pragma unroll
            for (int j = 0; j < 8; ++j)
                #pragma unroll
                for (int p = 0; p < 4; ++p)
                    acs[i][j][p] = __expf(acs[i][j][p] - m_[i][p]);
        #pragma unroll
        for (int i = 0; i < 2; ++i)
            #pragma unroll
            for (int p = 0; p < 4; ++p) {
                float s = 0.f;
                #pragma unroll
                for (int j = 0; j < 8; ++j) s += acs[i][j][p];
                s += __shfl_xor(s, 1, 64);
                s += __shfl_xor(s, 2, 64);
                s += __shfl_xor(s, 4, 64);
                s += __shfl_xor(s, 8, 64);
                l_[i][p] = l_[i][p] * sc[i][p] + s;
            }
        #pragma unroll
        for (int i = 0; i < 2; ++i)
            #pragma unroll
            for (int j2 = 0; j2 < 4; ++j2)
                #pragma unroll
                for (int p = 0; p < 4; ++p)
                    aco[i][j2][p] *= sc[i][p];

        __syncthreads();

        #pragma unroll
        for (int i = 0; i < 2; ++i)
            #pragma unroll
            for (int j = 0; j < 8; ++j)
                #pragma unroll
                for (int p = 0; p < 4; ++p)
                    KP[(w * 32 + i * 16 + kg * 4 + p) * 136 + j * 16 + lr] =
                        f2bf(acs[i][j][p]);
        __syncthreads();

        #pragma unroll
        for (int ks = 0; ks < 4; ++ks) {
            bf16x8 pa[2], pb[4];
            #pragma unroll
            for (int i = 0; i < 2; ++i)
                pa[i] = *(const bf16x8*)&KP[(w * 32 + i * 16 + lr) * 136 + ks * 32 + kg * 8];
            #pragma unroll
            for (int j2 = 0; j2 < 4; ++j2) {
                const int d = j2 * 16 + lr;
                pb[j2] = *(const bf16x8*)&Vs[d * 128 + (((ks * 4 + kg) ^ (d & 7)) << 3)];
            }
            #pragma unroll
            for (int i = 0; i < 2; ++i)
                #pragma unroll
                for (int j2 = 0; j2 < 4; ++j2)
                    aco[i][j2] = __builtin_amdgcn_mfma_f32_16x16x32_bf16(
                        pa[i], pb[j2], aco[i][j2], 0, 0, 0);
        }
        __syncthreads();

        if (nx) {
            #pragma unroll
            for (int it = 0; it < 4; ++it)
                *(u32x4*)(KP + tid * 8 + it * 2048) = kpre[it];
            #pragma unroll
            for (int it = 0; it < 4; ++it)
                *(u32x4*)(Vs + tid * 8 + it * 2048) = vpre[it];
            __syncthreads();
        }
    }

    #pragma unroll
    for (int i = 0; i < 2; ++i)
        #pragma unroll
        for (int j2 = 0; j2 < 4; ++j2)
            #pragma unroll
            for (int p = 0; p < 4; ++p) {
                const int row = zb * TSEQ + qb * 128 + w * 32 + i * 16 + kg * 4 + p;
                const int col = zh * HDIM + j2 * 16 + lr;
                O[(long long)row * DMODEL + col] = f2bf(aco[i][j2][p] / l_[i][p]);
            }
}

// ---------------------------------------------------------------------------
// 256x256x(BK=64) 8-wave 8-phase GEMM. M fixed at 2048 (8 rows of 256).
// PEPI=0: f32 C (lm_head). PEPI=1: bf16 C with per-z K-offset (kz elements)
// and C-offset (czs elements) — split-K partials.
// ---------------------------------------------------------------------------
template<int PEPI>
__global__ __launch_bounds__(512, 2) void gemm256_k(
    const short* __restrict__ A, const short* __restrict__ B,
    void* __restrict__ Cg, int K, int lda, int ldb, int ldc, int gx,
    long long kz, long long czs)
{
    extern __shared__ short smem[];

    const int nwg = gridDim.x;
    int wg = blockIdx.x;
    int sw = (wg & 7) * (nwg >> 3) + (wg >> 3);
    const int bx = sw >> 3, by = sw & 7;
    const int bn0 = bx * 256, bm0 = by * 256;
    const int zz = blockIdx.z;

    A += zz * kz;
    B += zz * kz;

    const int tid  = threadIdx.x;
    const int w    = tid >> 6, lane = tid & 63;
    const int wm   = w >> 2, wn = w & 3;
    const int lr   = lane & 15, kg = lane >> 4;

    const int r0  = tid >> 3;
    const int pc  = tid & 7;
    const int lc0 = pc ^ (r0 & 7);
    const int r1  = r0 + 64;
    const int lc1 = pc ^ (r1 & 7);

    f32x4 acc[2][2][4][2] = {};
    const int nk = K >> 6;

    auto stage = [&](int buf, int isA, int h, int kk) {
        const short* gp = isA ? A : B;
        const int    ld = isA ? lda : ldb;
        const long long rb = (long long)((isA ? bm0 : bn0) + h * 128);
        short* lp = smem + buf * 32768 + (isA ? 0 : 16384) + h * 8192;
        llds16(gp + (rb + r0) * ld + kk + lc0 * 8, lp + w * 512);
        llds16(gp + (rb + r1) * ld + kk + lc1 * 8, lp + 4096 + w * 512);
    };

#define PHASE(BUF, QM, QN, ISA, H, DOWAIT)                                      \
    do {                                                                        \
        const short* Ah = smem + (BUF) * 32768 + (QM) * 8192;                   \
        const short* Bh = smem + (BUF) * 32768 + 16384 + (QN) * 8192;           \
        bf16x8 af[2][4], bfr[2][2];                                             \
        _Pragma("unroll")                                                       \
        for (int s2 = 0; s2 < 2; ++s2) {                                        \
            _Pragma("unroll")                                                   \
            for (int i = 0; i < 4; ++i) {                                       \
                const int ra = wm * 64 + i * 16 + lr;                           \
                af[s2][i] = *(const bf16x8*)                                    \
                    &Ah[ra * 64 + (((s2 * 4 + kg) ^ (ra & 7)) << 3)];           \
            }                                                                   \
            _Pragma("unroll")                                                   \
            for (int j = 0; j < 2; ++j) {                                       \
                const int rb2 = wn * 32 + j * 16 + lr;                          \
                bfr[s2][j] = *(const bf16x8*)                                   \
                    &Bh[rb2 * 64 + (((s2 * 4 + kg) ^ (rb2 & 7)) << 3)];         \
            }                                                                   \
        }                                                                       \
        if (pf) stage(nb, ISA, H, kk);                                          \
        BAR();                                                                  \
        __builtin_amdgcn_s_setprio(1);                                          \
        _Pragma("unroll")                                                       \
        for (int s2 = 0; s2 < 2; ++s2)                                          \
            _Pragma("unroll")                                                   \
            for (int i = 0; i < 4; ++i)                                         \
                _Pragma("unroll")                                               \
                for (int j = 0; j < 2; ++j)                                     \
                    acc[QM][QN][i][j] = __builtin_amdgcn_mfma_f32_16x16x32_bf16(\
                        af[s2][i], bfr[s2][j], acc[QM][QN][i][j], 0, 0, 0);     \
        __builtin_amdgcn_s_setprio(0);                                          \
        DOWAIT;                                                                 \
        BAR();                                                                  \
    } while (0)

    stage(0, 1, 0, 0);
    stage(0, 0, 0, 0);
    stage(0, 1, 1, 0);
    stage(0, 0, 1, 0);
    if (nk > 1) { VMW4(); } else { VMW0(); }
    BAR();

    for (int t = 0; t < nk - 1; ++t) {
        const int  buf = t & 1, nb = buf ^ 1;
        const int  kk  = (t + 1) << 6;
        const bool pf  = true;
        PHASE(buf, 0, 0, 1, 0, VMW4());
        PHASE(buf, 1, 0, 0, 0, VMW4());
        PHASE(buf, 1, 1, 1, 1, (void)0);
        PHASE(buf, 0, 1, 0, 1, VMW4());
    }
    {
        const int  buf = (nk - 1) & 1, nb = buf ^ 1; (void)nb;
        const int  kk  = 0;
        const bool pf  = false;
        PHASE(buf, 0, 0, 1, 0, VMW2());
        PHASE(buf, 1, 0, 0, 0, VMW0());
        PHASE(buf, 1, 1, 1, 1, (void)0);
        PHASE(buf, 0, 1, 0, 1, (void)0);
    }
#undef PHASE

    float* Cf = (float*)Cg;
    short* Cs = (short*)Cg + zz * czs;
    #pragma unroll
    for (int qm = 0; qm < 2; ++qm)
        #pragma unroll
        for (int qn = 0; qn < 2; ++qn)
            #pragma unroll
            for (int i = 0; i < 4; ++i)
                #pragma unroll
                for (int j = 0; j < 2; ++j) {
                    const int gr = bm0 + qm * 128 + wm * 64 + i * 16 + kg * 4;
                    const int gc = bn0 + qn * 128 + wn * 32 + j * 16 + lr;
                    #pragma unroll
                    for (int p = 0; p < 4; ++p) {
                        if (PEPI == 0)
                            Cf[(long long)(gr + p) * ldc + gc] = acc[qm][qn][i][j][p];
                        else
                            Cs[(long long)(gr + p) * ldc + gc] = f2bf(acc[qm][qn][i][j][p]);
                    }
                }
}

// ---------------------------------------------------------------------------
// 128x(BN) double-buffered 2-phase GEMM. A bf16 [M][K], B bf16 [N][K].
// EPI: 0=f32 swapped float4, 3=bf16 gelu swapped s16x4,
//      5=bf16 plain swapped s16x4 (split-K partials),
//      4=qkv: Q,K scalar bf16 -> Cg; V cols (>=2048) transposed to aux.
// ---------------------------------------------------------------------------
template<int BN, int EPI>
__global__ __launch_bounds__(256) void gemm_k(
    const short* __restrict__ Ag, const short* __restrict__ Bg,
    void* __restrict__ Cg, const float* __restrict__ bias,
    short* __restrict__ aux,
    int M, int N, int K, int lda, int ldb, int ldc,
    long long sAz, long long sBz, long long sCz,
    float scale, int swz)
{
    int bx = blockIdx.x, by = blockIdx.y;
    if (swz) {
        const int gx = gridDim.x;
        const int nwg = gx * gridDim.y;
        if ((nwg & 7) == 0) {
            int wg = by * gx + bx;
            int wg2 = (wg & 7) * (nwg >> 3) + (wg >> 3);
            bx = wg2 % gx; by = wg2 / gx;
        }
    }
    const int bn0 = bx * BN, bm0 = by * 128;
    const int zz = blockIdx.z;

    const short* A = Ag + zz * sAz;
    const short* B = Bg + zz * sBz;

    __shared__ short Als[2][128 * 64];
    __shared__ short Bls[2][BN * 64];

    const int tid  = threadIdx.x;
    const int lane = tid & 63;
    const int wave = tid >> 6;
    constexpr int WMS = (BN == 128) ? 64 : 32;
    constexpr int MI  = (BN == 128) ? 4 : 2;
    constexpr int NJ  = 4;
    constexpr bool SW = (EPI == 0 || EPI == 3 || EPI == 5);
    const int wm = (BN == 128) ? (wave >> 1) : wave;
    const int wn = (BN == 128) ? (wave & 1) : 0;
    const int lr = lane & 15, kg = lane >> 4;
    const int xv = (lr & 7) << 4;

    const int sr = tid >> 3;
    const int sc = (tid & 7) ^ (sr & 7);
    const short* aP = A + (long long)(bm0 + sr) * lda + sc * 8;
    const short* bP = B + (long long)(bn0 + sr) * ldb + sc * 8;

    f32x4 acc[MI][NJ] = {};
    const int nk = K >> 6;

    auto stage = [&](int buf, int kt) {
        const int k0 = kt << 6;
        short* aL = &Als[buf][wave * 512];
        short* bL = &Bls[buf][wave * 512];
        #pragma unroll
        for (int it = 0; it < 4; ++it)
            llds16(aP + (long long)it * 32 * lda + k0, aL + it * 2048);
        #pragma unroll
        for (int it = 0; it < BN / 32; ++it)
            llds16(bP + (long long)it * 32 * ldb + k0, bL + it * 2048);
    };

    stage(0, 0);
    __syncthreads();

    for (int kt = 0; kt < nk; ++kt) {
        const int cb = kt & 1;
        if (kt + 1 < nk) stage(cb ^ 1, kt + 1);

        #pragma unroll
        for (int s = 0; s < 2; ++s) {
            const int ofs = (((s << 6) | (kg << 4)) ^ xv) >> 1;
            bf16x8 af[MI], bf[NJ];
            #pragma unroll
            for (int i = 0; i < MI; ++i)
                af[i] = *(const bf16x8*)&Als[cb][(wm * WMS + i * 16 + lr) * 64 + ofs];
            #pragma unroll
            for (int j = 0; j < NJ; ++j)
                bf[j] = *(const bf16x8*)&Bls[cb][(wn * 64 + j * 16 + lr) * 64 + ofs];
            #pragma unroll
            for (int i = 0; i < MI; ++i)
                #pragma unroll
                for (int j = 0; j < NJ; ++j) {
                    if (SW)
                        acc[i][j] = __builtin_amdgcn_mfma_f32_16x16x32_bf16(
                            bf[j], af[i], acc[i][j], 0, 0, 0);
                    else
                        acc[i][j] = __builtin_amdgcn_mfma_f32_16x16x32_bf16(
                            af[i], bf[j], acc[i][j], 0, 0, 0);
                }
        }
        __syncthreads();
    }

    short* Cs = (short*)Cg + zz * sCz;
    float* Cf = (float*)Cg + zz * sCz;
    #pragma unroll
    for (int i = 0; i < MI; ++i) {
        #pragma unroll
        for (int j = 0; j < NJ; ++j) {
            if (SW) {
                const int gr  = bm0 + wm * WMS + i * 16 + lr;
                const int gc0 = bn0 + wn * 64 + j * 16 + kg * 4;
                if (EPI == 0) {
                    *(float4*)&Cf[(long long)gr * ldc + gc0] =
                        *(const float4*)&acc[i][j];
                } else if (EPI == 5) {
                    s16x4 ov;
                    #pragma unroll
                    for (int p = 0; p < 4; ++p) ov[p] = f2bf(acc[i][j][p]);
                    *(s16x4*)&Cs[(long long)gr * ldc + gc0] = ov;
                } else {
                    float4 bb = *(const float4*)&bias[gc0];
                    s16x4 ov;
                    #pragma unroll
                    for (int p = 0; p < 4; ++p) {
                        float v = acc[i][j][p] + ((const float*)&bb)[p];
                        v = 0.5f * v * (1.0f + erff(v * 0.70710678118654752f));
                        ov[p] = f2bf(v);
                    }
                    *(s16x4*)&Cs[(long long)gr * ldc + gc0] = ov;
                }
            } else {
                const int gr = bm0 + wm * WMS + i * 16 + kg * 4;
                const int gc = bn0 + wn * 64 + j * 16 + lr;
                if (EPI == 4 && gc >= 2 * DMODEL) {
                    const int b = gr >> 10, t0 = gr & (TSEQ - 1);
                    const int h = (gc - 2 * DMODEL) >> 6, d = gc & 63;
                    s16x4 vv;
                    #pragma unroll
                    for (int p = 0; p < 4; ++p) vv[p] = f2bf(acc[i][j][p]);
                    *(s16x4*)&aux[((long long)(b * NHEAD + h) * HDIM + d) * TSEQ + t0] = vv;
                } else {
                    #pragma unroll
                    for (int p = 0; p < 4; ++p)
                        Cs[(long long)(gr + p) * ldc + gc] = f2bf(acc[i][j][p] * scale);
                }
            }
        }
    }
}

// ---------------------------------------------------------------------------
// wave-per-row fused split-K reduce (bf16 partials) + residual + LayerNorm
// ---------------------------------------------------------------------------
template<int NP>
__global__ __launch_bounds__(256) void fredln_k(
    const short* __restrict__ fp, long long pstride,
    const float* __restrict__ bias, float* __restrict__ x,
    const float* __restrict__ lw, const float* __restrict__ lb,
    short* __restrict__ o)
{
    const int row  = blockIdx.x * 4 + (threadIdx.x >> 6);
    const int lane = threadIdx.x & 63;
    const long long base = (long long)row * DMODEL + lane * 16;
    const int cb = lane * 16;
    float4 v[4];
    #pragma unroll
    for (int q = 0; q < 4; ++q) {
        v[q] = *(const float4*)&x[base + q * 4];
        float4 bb = *(const float4*)&bias[cb + q * 4];
        v[q].x += bb.x; v[q].y += bb.y; v[q].z += bb.z; v[q].w += bb.w;
    }
    #pragma unroll
    for (int k = 0; k < NP; ++k) {
        const short* pp = &fp[k * pstride + base];
        s16x8 p0 = *(const s16x8*)pp;
        s16x8 p1 = *(const s16x8*)(pp + 8);
        #pragma unroll
        for (int q = 0; q < 4; ++q) {
            const int e = q * 4;
            float e0 = bf2f((e + 0 < 8) ? p0[e + 0] : p1[e + 0 - 8]);
            float e1 = bf2f((e + 1 < 8) ? p0[e + 1] : p1[e + 1 - 8]);
            float e2 = bf2f((e + 2 < 8) ? p0[e + 2] : p1[e + 2 - 8]);
            float e3 = bf2f((e + 3 < 8) ? p0[e + 3] : p1[e + 3 - 8]);
            v[q].x += e0; v[q].y += e1; v[q].z += e2; v[q].w += e3;
        }
    }
    #pragma unroll
    for (int q = 0; q < 4; ++q)
        *(float4*)&x[base + q * 4] = v[q];
    float s = 0.f, s2 = 0.f;
    #pragma unroll
    for (int q = 0; q < 4; ++q) {
        s  += v[q].x + v[q].y + v[q].z + v[q].w;
        s2 += v[q].x * v[q].x + v[q].y * v[q].y + v[q].z * v[q].z + v[q].w * v[q].w;
    }
    #pragma unroll
    for (int d = 1; d < 64; d <<= 1) {
        s  += __shfl_xor(s, d, 64);
        s2 += __shfl_xor(s2, d, 64);
    }
    const float mean = s * (1.0f / DMODEL);
    const float var  = s2 * (1.0f / DMODEL) - mean * mean;
    const float rs   = rsqrtf(var + 1e-5f);
    short ov[16];
    #pragma unroll
    for (int q = 0; q < 4; ++q) {
        float4 wv = *(const float4*)&lw[cb + q * 4];
        float4 bv = *(const float4*)&lb[cb + q * 4];
        ov[q * 4 + 0] = f2bf((v[q].x - mean) * rs * wv.x + bv.x);
        ov[q * 4 + 1] = f2bf((v[q].y - mean) * rs * wv.y + bv.y);
        ov[q * 4 + 2] = f2bf((v[q].z - mean) * rs * wv.z + bv.z);
        ov[q * 4 + 3] = f2bf((v[q].w - mean) * rs * wv.w + bv.w);
    }
    short* op = o + base;
    *(s16x8*)op       = *(s16x8*)&ov[0];
    *(s16x8*)(op + 8) = *(s16x8*)&ov[8];
}

// embed + LN(layer-0 ln1). One block per row.
__global__ __launch_bounds__(256) void embedln_k(
    const int* __restrict__ ids, const float* __restrict__ tok,
    const float* __restrict__ pos, float* __restrict__ x,
    const float* __restrict__ lw, const float* __restrict__ lb,
    short* __restrict__ o)
{
    const int row = blockIdx.x;
    const int t   = row & (TSEQ - 1);
    const int id  = ids[row];
    const int i   = threadIdx.x * 4;
    const long long base = (long long)row * DMODEL;
    float4 a = *(const float4*)&tok[(long long)id * DMODEL + i];
    float4 p = *(const float4*)&pos[(long long)t * DMODEL + i];
    float4 v;
    v.x = a.x + p.x; v.y = a.y + p.y; v.z = a.z + p.z; v.w = a.w + p.w;
    *(float4*)&x[base + i] = v;
    float s  = v.x + v.y + v.z + v.w;
    float s2 = v.x * v.x + v.y * v.y + v.z * v.z + v.w * v.w;
    s  = block_sum(s);
    s2 = block_sum(s2);
    const float mean = s * (1.0f / DMODEL);
    const float var  = s2 * (1.0f / DMODEL) - mean * mean;
    const float rs   = rsqrtf(var + 1e-5f);
    float4 wv = *(const float4*)&lw[i];
    float4 bv = *(const float4*)&lb[i];
    s16x4 ov;
    ov[0] = f2bf((v.x - mean) * rs * wv.x + bv.x);
    ov[1] = f2bf((v.y - mean) * rs * wv.y + bv.y);
    ov[2] = f2bf((v.z - mean) * rs * wv.z + bv.z);
    ov[3] = f2bf((v.w - mean) * rs * wv.w + bv.w);
    *(s16x4*)&o[base + i] = ov;
}

// ---------------------------------------------------------------------------
// transpose-convert core (64x64 tile) — weight conversion only
template<typename T>
DEV_INLINE void tcvt_body(const T* sp, short* dp, int lds_, int ldd,
                          int bx, int by, short (*ls)[68], int t)
{
    const int tr0 = by * 64, tc0 = bx * 64;
    const int rr = t >> 4, cc = (t & 15) * 4;
    #pragma unroll
    for (int q = 0; q < 4; ++q) {
        const int r = q * 16 + rr;
        if constexpr (sizeof(T) == 4) {
            float4 v = *(const float4*)&sp[(long long)(tr0 + r) * lds_ + tc0 + cc];
            ls[cc + 0][r] = f2bf(v.x); ls[cc + 1][r] = f2bf(v.y);
            ls[cc + 2][r] = f2bf(v.z); ls[cc + 3][r] = f2bf(v.w);
        } else {
            s16x4 v = *(const s16x4*)&sp[(long long)(tr0 + r) * lds_ + tc0 + cc];
            ls[cc + 0][r] = v[0]; ls[cc + 1][r] = v[1];
            ls[cc + 2][r] = v[2]; ls[cc + 3][r] = v[3];
        }
    }
    __syncthreads();
    #pragma unroll
    for (int q = 0; q < 4; ++q) {
        const int c = q * 16 + rr;
        s16x4 v;
        v[0] = ls[c][cc]; v[1] = ls[c][cc + 1]; v[2] = ls[c][cc + 2]; v[3] = ls[c][cc + 3];
        *(s16x4*)&dp[(long long)(tc0 + c) * ldd + tr0 + cc] = v;
    }
}

template<typename T>
__global__ __launch_bounds__(256) void tcvt_k(
    const T* __restrict__ src, short* __restrict__ dst,
    int lds_, int ldd, int Hdiv,
    long long sSb, long long sSh, long long sDb, long long sDh)
{
    __shared__ short ls[64][68];
    const int z = blockIdx.z, zb = z / Hdiv, zh = z - zb * Hdiv;
    tcvt_body<T>(src + zb * sSb + zh * sSh, dst + zb * sDb + zh * sDh,
                 lds_, ldd, blockIdx.x, blockIdx.y, ls, threadIdx.x);
}

// merged per-layer weight convert (!big path): 3072 blocks
__global__ __launch_bounds__(256) void wcvt_k(
    const float* __restrict__ qw, const float* __restrict__ ow,
    const float* __restrict__ f1, const float* __restrict__ f2,
    short* __restrict__ wq, short* __restrict__ wo,
    short* __restrict__ w1, short* __restrict__ w2)
{
    __shared__ short ls[64][68];
    const int id = blockIdx.x;
    const float* src; short* dst; int lds_, ldd, bx, by;
    if (id < 768)       { src = qw; dst = wq; lds_ = 3072; ldd = 1024; bx = id % 48;  by = id / 48; }
    else if (id < 1024) { int i = id - 768;  src = ow; dst = wo; lds_ = 1024; ldd = 1024; bx = i % 16; by = i / 16; }
    else if (id < 2048) { int i = id - 1024; src = f1; dst = w1; lds_ = 4096; ldd = 1024; bx = i % 64; by = i / 64; }
    else                { int i = id - 2048; src = f2; dst = w2; lds_ = 1024; ldd = 4096; bx = i % 16; by = i / 16; }
    tcvt_body<float>(src, dst, lds_, ldd, bx, by, ls, threadIdx.x);
}

// plain fp32 -> bf16 convert (n4 = count/4)
__global__ __launch_bounds__(256) void cvt_k(
    const float* __restrict__ s, short* __restrict__ d, int n4)
{
    int i = blockIdx.x * 256 + threadIdx.x;
    const int stride = gridDim.x * 256;
    for (; i < n4; i += stride) {
        float4 v = *(const float4*)&s[(long long)i * 4];
        s16x4 o = { f2bf(v.x), f2bf(v.y), f2bf(v.z), f2bf(v.w) };
        *(s16x4*)&d[(long long)i * 4] = o;
    }
}

// ---------------------------------------------------------------------------
extern "C" void kernel_launch(void* const* d_in, const int* in_sizes, int n_in,
                              void* d_out, int out_size, void* d_ws, size_t ws_size,
                              hipStream_t stream)
{
    const int*   ids  = (const int*)  d_in[0];
    const float* tok  = (const float*)d_in[1];
    const float* pos  = (const float*)d_in[2];
    const float* ln1w = (const float*)d_in[3];
    const float* ln1b = (const float*)d_in[4];
    const float* qkvw = (const float*)d_in[5];
    const float* outw = (const float*)d_in[6];
    const float* outb = (const float*)d_in[7];
    const float* ln2w = (const float*)d_in[8];
    const float* ln2b = (const float*)d_in[9];
    const float* fc1w = (const float*)d_in[10];
    const float* fc1b = (const float*)d_in[11];
    const float* fc2w = (const float*)d_in[12];
    const float* fc2b = (const float*)d_in[13];
    const float* lnfw = (const float*)d_in[14];
    const float* lnfb = (const float*)d_in[15];
    float* out = (float*)d_out;

    char* ws = (char*)d_ws;
    const size_t MB = 1024 * 1024;
    float* x    = (float*)(ws);             //  0-8   f32 residual
    short* hb   = (short*)(ws + 8  * MB);   //  8-12  bf16 [2048][1024]
    short* qkvb = (short*)(ws + 12 * MB);   // 12-24  bf16 [2048][3072] (V unused)
    short* g    = (short*)(ws + 24 * MB);   // 24-40  bf16 [2048][4096]
    short* Vt   = (short*)(ws + 40 * MB);   // 40-44  bf16 [32][64][1024]
    short* fp   = (short*)(ws + 44 * MB);   // 44-76  bf16 [8][2048][1024] partials
    short* tokb = (short*)(ws + 12 * MB);   // lm_head phase only (aliases dead bufs)

    const bool big = ws_size >= (size_t)272 * MB;
    short* wq = (short*)(ws + 80 * MB);
    short *wo, *w1, *w2;
    if (big) {
        wo = (short*)(ws + 128 * MB);
        w1 = (short*)(ws + 144 * MB);
        w2 = (short*)(ws + 208 * MB);       // ends 272
    } else {
        wo = (short*)(ws + 86 * MB);
        w1 = (short*)(ws + 88 * MB);
        w2 = (short*)(ws + 96 * MB);        // ends 104
    }

    const long long LWQ = 3072LL * 1024, LWO = 1024LL * 1024;
    const long long LW1 = 4096LL * 1024, LW2 = 1024LL * 4096;
    const long long MD  = (long long)MTOK * DMODEL;

    hipFuncSetAttribute((const void*)gemm256_k<0>,
                        hipFuncAttributeMaxDynamicSharedMemorySize, 131072);
    hipFuncSetAttribute((const void*)gemm256_k<1>,
                        hipFuncAttributeMaxDynamicSharedMemorySize, 131072);

    dim3 blk(256);
    embedln_k<<<MTOK, blk, 0, stream>>>(ids, tok, pos, x, ln1w, ln1b, hb);

    if (big) {
        tcvt_k<float><<<dim3(48, 16, 8), blk, 0, stream>>>(qkvw, wq, 3072, 1024, 1, LWQ, 0, LWQ, 0);
        tcvt_k<float><<<dim3(16, 16, 8), blk, 0, stream>>>(outw, wo, 1024, 1024, 1, LWO, 0, LWO, 0);
        tcvt_k<float><<<dim3(64, 16, 8), blk, 0, stream>>>(fc1w, w1, 4096, 1024, 1, LW1, 0, LW1, 0);
        tcvt_k<float><<<dim3(16, 64, 8), blk, 0, stream>>>(fc2w, w2, 1024, 4096, 1, LW2, 0, LW2, 0);
    }

    for (int l = 0; l < NLAYER; ++l) {
        short* wql = wq + (big ? l * LWQ : 0);
        short* wol = wo + (big ? l * LWO : 0);
        short* w1l = w1 + (big ? l * LW1 : 0);
        short* w2l = w2 + (big ? l * LW2 : 0);
        if (!big)
            wcvt_k<<<3072, blk, 0, stream>>>(
                qkvw + l * LWQ, outw + l * LWO, fc1w + l * LW1, fc2w + l * LW2,
                wql, wol, w1l, w2l);

        // qkv = ln1 @ Wqkv -> Q,K to qkvb; V transposed to Vt (EPI=4)
        gemm_k<128, 4><<<dim3(24, 16, 1), blk, 0, stream>>>(
            hb, wql, qkvb, nullptr, Vt,
            MTOK, 3 * DMODEL, DMODEL, DMODEL, DMODEL, 3 * DMODEL,
            0, 0, 0, 1.0f, 1);

        // fused attention -> hb (bf16)
        flash_k<<<dim3(8, BBATCH * NHEAD), blk, 0, stream>>>(qkvb, Vt, hb);

        // out-proj split-K=2 -> bf16 partials; x += sum + bias, hb = LN2(x)
        gemm_k<128, 5><<<dim3(8, 16, 2), blk, 0, stream>>>(
            hb, wol, fp, nullptr, nullptr,
            MTOK, DMODEL, 512, DMODEL, DMODEL, DMODEL,
            512, 512, MD, 1.0f, 1);
        fredln_k<2><<<MTOK / 4, blk, 0, stream>>>(
            fp, MD, outb + l * DMODEL, x,
            ln2w + l * DMODEL, ln2b + l * DMODEL, hb);

        // g = gelu(ln2 @ Wfc1 + b) -> bf16
        gemm_k<128, 3><<<dim3(32, 16, 1), blk, 0, stream>>>(
            hb, w1l, g, fc1b + (long long)l * 4 * DMODEL, nullptr,
            MTOK, 4 * DMODEL, DMODEL, DMODEL, DMODEL, 4 * DMODEL,
            0, 0, 0, 1.0f, 1);

        // fc2 via 256x256 8-phase split-K=8 -> bf16 partials (grid 32 x 8z)
        gemm256_k<1><<<dim3(32, 1, 8), dim3(512), 131072, stream>>>(
            g, w2l, fp, 512, 4 * DMODEL, 4 * DMODEL, DMODEL, 4,
            512, MD);
        const float* nlw = (l < 7) ? ln1w + (l + 1) * DMODEL : lnfw;
        const float* nlb = (l < 7) ? ln1b + (l + 1) * DMODEL : lnfb;
        fredln_k<8><<<MTOK / 4, blk, 0, stream>>>(
            fp, MD, fc2b + l * DMODEL, x, nlw, nlb, hb);
    }

    // tok_emb -> bf16 (tokb aliases dead activation buffers)
    cvt_k<<<2048, blk, 0, stream>>>(tok, tokb, NVOCAB * DMODEL / 4);

    // logits = lnf @ tok_emb^T via 256x256 8-phase kernel (grid = 125*8)
    gemm256_k<0><<<dim3((NVOCAB / 256) * (MTOK / 256)), dim3(512), 131072, stream>>>(
        hb, tokb, out, DMODEL, DMODEL, DMODEL, NVOCAB, NVOCAB / 256, 0, 0);
}

// Round 15
// 1549.061 us; speedup vs baseline: 1.0282x; 1.0282x over previous
//
#include <hip/hip_runtime.h>
#include <hip/hip_bf16.h>
#include <math.h>

// ---------------------------------------------------------------------------
// GPT forward, round 15: revert to the round-12 configuration (best measured:
// 1552 us). fc2 split-K=4 in the 128x128 2-phase GEMM, bf16 partials,
// lm_head via 256x256 8-phase counted-vmcnt GEMM.
// ---------------------------------------------------------------------------

#define DEV_INLINE __device__ __forceinline__

typedef float  f32x4  __attribute__((ext_vector_type(4)));
typedef __bf16 bf16x8 __attribute__((ext_vector_type(8)));
typedef short  s16x4  __attribute__((ext_vector_type(4)));
typedef short  s16x8  __attribute__((ext_vector_type(8)));
typedef unsigned int u32x4 __attribute__((ext_vector_type(4)));

#define BBATCH 2
#define TSEQ   1024
#define DMODEL 1024
#define NHEAD  16
#define HDIM   64
#define NLAYER 8
#define NVOCAB 32000
#define MTOK   (BBATCH*TSEQ)   // 2048

DEV_INLINE short f2bf(float f) {
    __bf16 h = (__bf16)f;
    union { __bf16 h; short s; } u; u.h = h; return u.s;
}
DEV_INLINE float bf2f(short s) {
    union { unsigned u; float f; } x; x.u = ((unsigned)(unsigned short)s) << 16;
    return x.f;
}

typedef const __attribute__((address_space(1))) unsigned int* gas_t;
typedef __attribute__((address_space(3))) unsigned int* las_t;
DEV_INLINE void llds16(const void* g, void* l) {
    __builtin_amdgcn_global_load_lds((gas_t)g, (las_t)l, 16, 0, 0);
}

#define BAR()  asm volatile("s_barrier" ::: "memory")
#define VMW4() asm volatile("s_waitcnt vmcnt(4)" ::: "memory")
#define VMW2() asm volatile("s_waitcnt vmcnt(2)" ::: "memory")
#define VMW0() asm volatile("s_waitcnt vmcnt(0)" ::: "memory")

DEV_INLINE float block_sum(float v) {
    __shared__ float sb[4];
    #pragma unroll
    for (int o = 32; o > 0; o >>= 1) v += __shfl_down(v, o, 64);
    if ((threadIdx.x & 63) == 0) sb[threadIdx.x >> 6] = v;
    __syncthreads();
    float r = sb[0] + sb[1] + sb[2] + sb[3];
    __syncthreads();
    return r;
}

// ---------------------------------------------------------------------------
// Flash attention (round-8 structure): grid (8 q-blocks, 32 bh), 256 threads;
// KV tiles 128; reg-prefetch of next K/V tile.
// ---------------------------------------------------------------------------
__global__ __launch_bounds__(256) void flash_k(
    const short* __restrict__ qkv, const short* __restrict__ Vt,
    short* __restrict__ O)
{
    const int qb = blockIdx.x;          // 0..7
    const int z  = blockIdx.y;          // 0..31
    const int zb = z >> 4, zh = z & 15;

    __shared__ short Qs[128 * 64];
    __shared__ short KP[128 * 136];
    __shared__ short Vs[64 * 128];

    const int tid  = threadIdx.x;
    const int w    = tid >> 6, lane = tid & 63;
    const int lr   = lane & 15, kg = lane >> 4;

    const long long qbase = (long long)zb * TSEQ * 3072;
    const short* Qg = qkv + qbase + zh * HDIM;
    const short* Kg = qkv + qbase + DMODEL + zh * HDIM;
    const short* Vg = Vt + (long long)z * (HDIM * TSEQ);

    const int sr   = tid >> 3, pc = tid & 7;
    const int lc   = pc ^ (sr & 7);
    const int sr16 = tid >> 4, pc16 = tid & 15;

    {
        const short* qp = Qg + (long long)(qb * 128 + sr) * 3072 + lc * 8;
        const short* kp = Kg + (long long)(0 + sr) * 3072 + lc * 8;
        #pragma unroll
        for (int it = 0; it < 4; ++it) {
            llds16(qp + (long long)it * 32 * 3072, Qs + tid * 8 + it * 2048);
            llds16(kp + (long long)it * 32 * 3072, KP + tid * 8 + it * 2048);
        }
        #pragma unroll
        for (int it = 0; it < 4; ++it) {
            const int r = it * 16 + sr16;
            const int lc2 = pc16 ^ (r & 7);
            llds16(Vg + (long long)r * TSEQ + 0 + lc2 * 8, Vs + tid * 8 + it * 2048);
        }
    }
    __syncthreads();
    bf16x8 afq[2][2];
    #pragma unroll
    for (int s = 0; s < 2; ++s)
        #pragma unroll
        for (int i = 0; i < 2; ++i) {
            const int r = w * 32 + i * 16 + lr;
            afq[s][i] = *(const bf16x8*)&Qs[r * 64 + (((s * 4 + kg) ^ (r & 7)) << 3)];
        }

    f32x4 aco[2][4] = {};
    float m_[2][4], l_[2][4];
    #pragma unroll
    for (int i = 0; i < 2; ++i)
        #pragma unroll
        for (int p = 0; p < 4; ++p) { m_[i][p] = -1e30f; l_[i][p] = 0.f; }

    const int nt = qb + 1;
    for (int t = 0; t < nt; ++t) {
        u32x4 kpre[4], vpre[4];
        const bool nx = (t + 1 < nt);
        if (nx) {
            const int kn = (t + 1) * 128;
            #pragma unroll
            for (int it = 0; it < 4; ++it)
                kpre[it] = *(const u32x4*)(Kg + (long long)(kn + sr + it * 32) * 3072 + lc * 8);
            #pragma unroll
            for (int it = 0; it < 4; ++it) {
                const int r = it * 16 + sr16;
                const int lc2 = pc16 ^ (r & 7);
                vpre[it] = *(const u32x4*)(Vg + (long long)r * TSEQ + kn + lc2 * 8);
            }
            __builtin_amdgcn_sched_barrier(0);
        }

        f32x4 acs[2][8] = {};
        #pragma unroll
        for (int s = 0; s < 2; ++s)
            #pragma unroll
            for (int j = 0; j < 8; ++j) {
                const int rk = j * 16 + lr;
                bf16x8 bk = *(const bf16x8*)&KP[rk * 64 + (((s * 4 + kg) ^ (rk & 7)) << 3)];
                #pragma unroll
                for (int i = 0; i < 2; ++i)
                    acs[i][j] = __builtin_amdgcn_mfma_f32_16x16x32_bf16(
                        afq[s][i], bk, acs[i][j], 0, 0, 0);
            }

        #pragma unroll
        for (int i = 0; i < 2; ++i)
            #pragma unroll
            for (int j = 0; j < 8; ++j)
                #pragma unroll
                for (int p = 0; p < 4; ++p) {
                    float v = acs[i][j][p] * 0.125f;
                    if (t == qb && (j * 16 + lr) > (w * 32 + i * 16 + kg * 4 + p))
                        v = -1e30f;
                    acs[i][j][p] = v;
                }

        float sc[2][4];
        #pragma unroll
        for (int i = 0; i < 2; ++i)
            #pragma unroll
            for (int p = 0; p < 4; ++p) {
                float r = acs[i][0][p];
                #pragma unroll
                for (int j = 1; j < 8; ++j) r = fmaxf(r, acs[i][j][p]);
                r = fmaxf(r, __shfl_xor(r, 1, 64));
                r = fmaxf(r, __shfl_xor(r, 2, 64));
                r = fmaxf(r, __shfl_xor(r, 4, 64));
                r = fmaxf(r, __shfl_xor(r, 8, 64));
                const float mn = fmaxf(m_[i][p], r);
                sc[i][p] = __expf(m_[i][p] - mn);
                m_[i][p] = mn;
            }
        #pragma unroll
        for (int i = 0; i < 2; ++i)
            #pragma unroll
            for (int j = 0; j < 8; ++j)
                #pragma unroll
                for (int p = 0; p < 4; ++p)
                    acs[i][j][p] = __expf(acs[i][j][p] - m_[i][p]);
        #pragma unroll
        for (int i = 0; i < 2; ++i)
            #pragma unroll
            for (int p = 0; p < 4; ++p) {
                float s = 0.f;
                #pragma unroll
                for (int j = 0; j < 8; ++j) s += acs[i][j][p];
                s += __shfl_xor(s, 1, 64);
                s += __shfl_xor(s, 2, 64);
                s += __shfl_xor(s, 4, 64);
                s += __shfl_xor(s, 8, 64);
                l_[i][p] = l_[i][p] * sc[i][p] + s;
            }
        #pragma unroll
        for (int i = 0; i < 2; ++i)
            #pragma unroll
            for (int j2 = 0; j2 < 4; ++j2)
                #pragma unroll
                for (int p = 0; p < 4; ++p)
                    aco[i][j2][p] *= sc[i][p];

        __syncthreads();

        #pragma unroll
        for (int i = 0; i < 2; ++i)
            #pragma unroll
            for (int j = 0; j < 8; ++j)
                #pragma unroll
                for (int p = 0; p < 4; ++p)
                    KP[(w * 32 + i * 16 + kg * 4 + p) * 136 + j * 16 + lr] =
                        f2bf(acs[i][j][p]);
        __syncthreads();

        #pragma unroll
        for (int ks = 0; ks < 4; ++ks) {
            bf16x8 pa[2], pb[4];
            #pragma unroll
            for (int i = 0; i < 2; ++i)
                pa[i] = *(const bf16x8*)&KP[(w * 32 + i * 16 + lr) * 136 + ks * 32 + kg * 8];
            #pragma unroll
            for (int j2 = 0; j2 < 4; ++j2) {
                const int d = j2 * 16 + lr;
                pb[j2] = *(const bf16x8*)&Vs[d * 128 + (((ks * 4 + kg) ^ (d & 7)) << 3)];
            }
            #pragma unroll
            for (int i = 0; i < 2; ++i)
                #pragma unroll
                for (int j2 = 0; j2 < 4; ++j2)
                    aco[i][j2] = __builtin_amdgcn_mfma_f32_16x16x32_bf16(
                        pa[i], pb[j2], aco[i][j2], 0, 0, 0);
        }
        __syncthreads();

        if (nx) {
            #pragma unroll
            for (int it = 0; it < 4; ++it)
                *(u32x4*)(KP + tid * 8 + it * 2048) = kpre[it];
            #pragma unroll
            for (int it = 0; it < 4; ++it)
                *(u32x4*)(Vs + tid * 8 + it * 2048) = vpre[it];
            __syncthreads();
        }
    }

    #pragma unroll
    for (int i = 0; i < 2; ++i)
        #pragma unroll
        for (int j2 = 0; j2 < 4; ++j2)
            #pragma unroll
            for (int p = 0; p < 4; ++p) {
                const int row = zb * TSEQ + qb * 128 + w * 32 + i * 16 + kg * 4 + p;
                const int col = zh * HDIM + j2 * 16 + lr;
                O[(long long)row * DMODEL + col] = f2bf(aco[i][j2][p] / l_[i][p]);
            }
}

// ---------------------------------------------------------------------------
// 256x256x(BK=64) 8-wave 8-phase GEMM, f32 output (lm_head). Round-8 form.
// ---------------------------------------------------------------------------
__global__ __launch_bounds__(512, 2) void gemm256_k(
    const short* __restrict__ A, const short* __restrict__ B,
    float* __restrict__ C, int K, int lda, int ldb, int ldc, int gx)
{
    extern __shared__ short smem[];

    const int nwg = gridDim.x;
    int wg = blockIdx.x;
    int sw = (wg & 7) * (nwg >> 3) + (wg >> 3);
    const int bx = sw >> 3, by = sw & 7;
    const int bn0 = bx * 256, bm0 = by * 256;

    const int tid  = threadIdx.x;
    const int w    = tid >> 6, lane = tid & 63;
    const int wm   = w >> 2, wn = w & 3;
    const int lr   = lane & 15, kg = lane >> 4;

    const int r0  = tid >> 3;
    const int pc  = tid & 7;
    const int lc0 = pc ^ (r0 & 7);
    const int r1  = r0 + 64;
    const int lc1 = pc ^ (r1 & 7);

    f32x4 acc[2][2][4][2] = {};
    const int nk = K >> 6;

    auto stage = [&](int buf, int isA, int h, int kk) {
        const short* gp = isA ? A : B;
        const int    ld = isA ? lda : ldb;
        const long long rb = (long long)((isA ? bm0 : bn0) + h * 128);
        short* lp = smem + buf * 32768 + (isA ? 0 : 16384) + h * 8192;
        llds16(gp + (rb + r0) * ld + kk + lc0 * 8, lp + w * 512);
        llds16(gp + (rb + r1) * ld + kk + lc1 * 8, lp + 4096 + w * 512);
    };

#define PHASE(BUF, QM, QN, ISA, H, DOWAIT)                                      \
    do {                                                                        \
        const short* Ah = smem + (BUF) * 32768 + (QM) * 8192;                   \
        const short* Bh = smem + (BUF) * 32768 + 16384 + (QN) * 8192;           \
        bf16x8 af[2][4], bfr[2][2];                                             \
        _Pragma("unroll")                                                       \
        for (int s2 = 0; s2 < 2; ++s2) {                                        \
            _Pragma("unroll")                                                   \
            for (int i = 0; i < 4; ++i) {                                       \
                const int ra = wm * 64 + i * 16 + lr;                           \
                af[s2][i] = *(const bf16x8*)                                    \
                    &Ah[ra * 64 + (((s2 * 4 + kg) ^ (ra & 7)) << 3)];           \
            }                                                                   \
            _Pragma("unroll")                                                   \
            for (int j = 0; j < 2; ++j) {                                       \
                const int rb2 = wn * 32 + j * 16 + lr;                          \
                bfr[s2][j] = *(const bf16x8*)                                   \
                    &Bh[rb2 * 64 + (((s2 * 4 + kg) ^ (rb2 & 7)) << 3)];         \
            }                                                                   \
        }                                                                       \
        if (pf) stage(nb, ISA, H, kk);                                          \
        BAR();                                                                  \
        __builtin_amdgcn_s_setprio(1);                                          \
        _Pragma("unroll")                                                       \
        for (int s2 = 0; s2 < 2; ++s2)                                          \
            _Pragma("unroll")                                                   \
            for (int i = 0; i < 4; ++i)                                         \
                _Pragma("unroll")                                               \
                for (int j = 0; j < 2; ++j)                                     \
                    acc[QM][QN][i][j] = __builtin_amdgcn_mfma_f32_16x16x32_bf16(\
                        af[s2][i], bfr[s2][j], acc[QM][QN][i][j], 0, 0, 0);     \
        __builtin_amdgcn_s_setprio(0);                                          \
        DOWAIT;                                                                 \
        BAR();                                                                  \
    } while (0)

    stage(0, 1, 0, 0);
    stage(0, 0, 0, 0);
    stage(0, 1, 1, 0);
    stage(0, 0, 1, 0);
    if (nk > 1) { VMW4(); } else { VMW0(); }
    BAR();

    for (int t = 0; t < nk - 1; ++t) {
        const int  buf = t & 1, nb = buf ^ 1;
        const int  kk  = (t + 1) << 6;
        const bool pf  = true;
        PHASE(buf, 0, 0, 1, 0, VMW4());
        PHASE(buf, 1, 0, 0, 0, VMW4());
        PHASE(buf, 1, 1, 1, 1, (void)0);
        PHASE(buf, 0, 1, 0, 1, VMW4());
    }
    {
        const int  buf = (nk - 1) & 1, nb = buf ^ 1; (void)nb;
        const int  kk  = 0;
        const bool pf  = false;
        PHASE(buf, 0, 0, 1, 0, VMW2());
        PHASE(buf, 1, 0, 0, 0, VMW0());
        PHASE(buf, 1, 1, 1, 1, (void)0);
        PHASE(buf, 0, 1, 0, 1, (void)0);
    }
#undef PHASE

    #pragma unroll
    for (int qm = 0; qm < 2; ++qm)
        #pragma unroll
        for (int qn = 0; qn < 2; ++qn)
            #pragma unroll
            for (int i = 0; i < 4; ++i)
                #pragma unroll
                for (int j = 0; j < 2; ++j) {
                    const int gr = bm0 + qm * 128 + wm * 64 + i * 16 + kg * 4;
                    const int gc = bn0 + qn * 128 + wn * 32 + j * 16 + lr;
                    #pragma unroll
                    for (int p = 0; p < 4; ++p)
                        C[(long long)(gr + p) * ldc + gc] = acc[qm][qn][i][j][p];
                }
}

// ---------------------------------------------------------------------------
// 128x(BN) double-buffered 2-phase GEMM. A bf16 [M][K], B bf16 [N][K].
// EPI: 0=f32 swapped float4, 3=bf16 gelu swapped s16x4,
//      5=bf16 plain swapped s16x4 (split-K partials),
//      4=qkv: Q,K scalar bf16 -> Cg; V cols (>=2048) transposed to aux.
// ---------------------------------------------------------------------------
template<int BN, int EPI>
__global__ __launch_bounds__(256) void gemm_k(
    const short* __restrict__ Ag, const short* __restrict__ Bg,
    void* __restrict__ Cg, const float* __restrict__ bias,
    short* __restrict__ aux,
    int M, int N, int K, int lda, int ldb, int ldc,
    long long sAz, long long sBz, long long sCz,
    float scale, int swz)
{
    int bx = blockIdx.x, by = blockIdx.y;
    if (swz) {
        const int gx = gridDim.x;
        const int nwg = gx * gridDim.y;
        if ((nwg & 7) == 0) {
            int wg = by * gx + bx;
            int wg2 = (wg & 7) * (nwg >> 3) + (wg >> 3);
            bx = wg2 % gx; by = wg2 / gx;
        }
    }
    const int bn0 = bx * BN, bm0 = by * 128;
    const int zz = blockIdx.z;

    const short* A = Ag + zz * sAz;
    const short* B = Bg + zz * sBz;

    __shared__ short Als[2][128 * 64];
    __shared__ short Bls[2][BN * 64];

    const int tid  = threadIdx.x;
    const int lane = tid & 63;
    const int wave = tid >> 6;
    constexpr int WMS = (BN == 128) ? 64 : 32;
    constexpr int MI  = (BN == 128) ? 4 : 2;
    constexpr int NJ  = 4;
    constexpr bool SW = (EPI == 0 || EPI == 3 || EPI == 5);
    const int wm = (BN == 128) ? (wave >> 1) : wave;
    const int wn = (BN == 128) ? (wave & 1) : 0;
    const int lr = lane & 15, kg = lane >> 4;
    const int xv = (lr & 7) << 4;

    const int sr = tid >> 3;
    const int sc = (tid & 7) ^ (sr & 7);
    const short* aP = A + (long long)(bm0 + sr) * lda + sc * 8;
    const short* bP = B + (long long)(bn0 + sr) * ldb + sc * 8;

    f32x4 acc[MI][NJ] = {};
    const int nk = K >> 6;

    auto stage = [&](int buf, int kt) {
        const int k0 = kt << 6;
        short* aL = &Als[buf][wave * 512];
        short* bL = &Bls[buf][wave * 512];
        #pragma unroll
        for (int it = 0; it < 4; ++it)
            llds16(aP + (long long)it * 32 * lda + k0, aL + it * 2048);
        #pragma unroll
        for (int it = 0; it < BN / 32; ++it)
            llds16(bP + (long long)it * 32 * ldb + k0, bL + it * 2048);
    };

    stage(0, 0);
    __syncthreads();

    for (int kt = 0; kt < nk; ++kt) {
        const int cb = kt & 1;
        if (kt + 1 < nk) stage(cb ^ 1, kt + 1);

        #pragma unroll
        for (int s = 0; s < 2; ++s) {
            const int ofs = (((s << 6) | (kg << 4)) ^ xv) >> 1;
            bf16x8 af[MI], bf[NJ];
            #pragma unroll
            for (int i = 0; i < MI; ++i)
                af[i] = *(const bf16x8*)&Als[cb][(wm * WMS + i * 16 + lr) * 64 + ofs];
            #pragma unroll
            for (int j = 0; j < NJ; ++j)
                bf[j] = *(const bf16x8*)&Bls[cb][(wn * 64 + j * 16 + lr) * 64 + ofs];
            #pragma unroll
            for (int i = 0; i < MI; ++i)
                #pragma unroll
                for (int j = 0; j < NJ; ++j) {
                    if (SW)
                        acc[i][j] = __builtin_amdgcn_mfma_f32_16x16x32_bf16(
                            bf[j], af[i], acc[i][j], 0, 0, 0);
                    else
                        acc[i][j] = __builtin_amdgcn_mfma_f32_16x16x32_bf16(
                            af[i], bf[j], acc[i][j], 0, 0, 0);
                }
        }
        __syncthreads();
    }

    short* Cs = (short*)Cg + zz * sCz;
    float* Cf = (float*)Cg + zz * sCz;
    #pragma unroll
    for (int i = 0; i < MI; ++i) {
        #pragma unroll
        for (int j = 0; j < NJ; ++j) {
            if (SW) {
                const int gr  = bm0 + wm * WMS + i * 16 + lr;
                const int gc0 = bn0 + wn * 64 + j * 16 + kg * 4;
                if (EPI == 0) {
                    *(float4*)&Cf[(long long)gr * ldc + gc0] =
                        *(const float4*)&acc[i][j];
                } else if (EPI == 5) {
                    s16x4 ov;
                    #pragma unroll
                    for (int p = 0; p < 4; ++p) ov[p] = f2bf(acc[i][j][p]);
                    *(s16x4*)&Cs[(long long)gr * ldc + gc0] = ov;
                } else {
                    float4 bb = *(const float4*)&bias[gc0];
                    s16x4 ov;
                    #pragma unroll
                    for (int p = 0; p < 4; ++p) {
                        float v = acc[i][j][p] + ((const float*)&bb)[p];
                        v = 0.5f * v * (1.0f + erff(v * 0.70710678118654752f));
                        ov[p] = f2bf(v);
                    }
                    *(s16x4*)&Cs[(long long)gr * ldc + gc0] = ov;
                }
            } else {
                const int gr = bm0 + wm * WMS + i * 16 + kg * 4;
                const int gc = bn0 + wn * 64 + j * 16 + lr;
                if (EPI == 4 && gc >= 2 * DMODEL) {
                    const int b = gr >> 10, t0 = gr & (TSEQ - 1);
                    const int h = (gc - 2 * DMODEL) >> 6, d = gc & 63;
                    s16x4 vv;
                    #pragma unroll
                    for (int p = 0; p < 4; ++p) vv[p] = f2bf(acc[i][j][p]);
                    *(s16x4*)&aux[((long long)(b * NHEAD + h) * HDIM + d) * TSEQ + t0] = vv;
                } else {
                    #pragma unroll
                    for (int p = 0; p < 4; ++p)
                        Cs[(long long)(gr + p) * ldc + gc] = f2bf(acc[i][j][p] * scale);
                }
            }
        }
    }
}

// ---------------------------------------------------------------------------
// wave-per-row fused split-K reduce (bf16 partials) + residual + LayerNorm
// ---------------------------------------------------------------------------
template<int NP>
__global__ __launch_bounds__(256) void fredln_k(
    const short* __restrict__ fp, long long pstride,
    const float* __restrict__ bias, float* __restrict__ x,
    const float* __restrict__ lw, const float* __restrict__ lb,
    short* __restrict__ o)
{
    const int row  = blockIdx.x * 4 + (threadIdx.x >> 6);
    const int lane = threadIdx.x & 63;
    const long long base = (long long)row * DMODEL + lane * 16;
    const int cb = lane * 16;
    float4 v[4];
    #pragma unroll
    for (int q = 0; q < 4; ++q) {
        v[q] = *(const float4*)&x[base + q * 4];
        float4 bb = *(const float4*)&bias[cb + q * 4];
        v[q].x += bb.x; v[q].y += bb.y; v[q].z += bb.z; v[q].w += bb.w;
    }
    #pragma unroll
    for (int k = 0; k < NP; ++k) {
        const short* pp = &fp[k * pstride + base];
        s16x8 p0 = *(const s16x8*)pp;
        s16x8 p1 = *(const s16x8*)(pp + 8);
        #pragma unroll
        for (int q = 0; q < 4; ++q) {
            const int e = q * 4;
            float e0 = bf2f((e + 0 < 8) ? p0[e + 0] : p1[e + 0 - 8]);
            float e1 = bf2f((e + 1 < 8) ? p0[e + 1] : p1[e + 1 - 8]);
            float e2 = bf2f((e + 2 < 8) ? p0[e + 2] : p1[e + 2 - 8]);
            float e3 = bf2f((e + 3 < 8) ? p0[e + 3] : p1[e + 3 - 8]);
            v[q].x += e0; v[q].y += e1; v[q].z += e2; v[q].w += e3;
        }
    }
    #pragma unroll
    for (int q = 0; q < 4; ++q)
        *(float4*)&x[base + q * 4] = v[q];
    float s = 0.f, s2 = 0.f;
    #pragma unroll
    for (int q = 0; q < 4; ++q) {
        s  += v[q].x + v[q].y + v[q].z + v[q].w;
        s2 += v[q].x * v[q].x + v[q].y * v[q].y + v[q].z * v[q].z + v[q].w * v[q].w;
    }
    #pragma unroll
    for (int d = 1; d < 64; d <<= 1) {
        s  += __shfl_xor(s, d, 64);
        s2 += __shfl_xor(s2, d, 64);
    }
    const float mean = s * (1.0f / DMODEL);
    const float var  = s2 * (1.0f / DMODEL) - mean * mean;
    const float rs   = rsqrtf(var + 1e-5f);
    short ov[16];
    #pragma unroll
    for (int q = 0; q < 4; ++q) {
        float4 wv = *(const float4*)&lw[cb + q * 4];
        float4 bv = *(const float4*)&lb[cb + q * 4];
        ov[q * 4 + 0] = f2bf((v[q].x - mean) * rs * wv.x + bv.x);
        ov[q * 4 + 1] = f2bf((v[q].y - mean) * rs * wv.y + bv.y);
        ov[q * 4 + 2] = f2bf((v[q].z - mean) * rs * wv.z + bv.z);
        ov[q * 4 + 3] = f2bf((v[q].w - mean) * rs * wv.w + bv.w);
    }
    short* op = o + base;
    *(s16x8*)op       = *(s16x8*)&ov[0];
    *(s16x8*)(op + 8) = *(s16x8*)&ov[8];
}

// embed + LN(layer-0 ln1). One block per row.
__global__ __launch_bounds__(256) void embedln_k(
    const int* __restrict__ ids, const float* __restrict__ tok,
    const float* __restrict__ pos, float* __restrict__ x,
    const float* __restrict__ lw, const float* __restrict__ lb,
    short* __restrict__ o)
{
    const int row = blockIdx.x;
    const int t   = row & (TSEQ - 1);
    const int id  = ids[row];
    const int i   = threadIdx.x * 4;
    const long long base = (long long)row * DMODEL;
    float4 a = *(const float4*)&tok[(long long)id * DMODEL + i];
    float4 p = *(const float4*)&pos[(long long)t * DMODEL + i];
    float4 v;
    v.x = a.x + p.x; v.y = a.y + p.y; v.z = a.z + p.z; v.w = a.w + p.w;
    *(float4*)&x[base + i] = v;
    float s  = v.x + v.y + v.z + v.w;
    float s2 = v.x * v.x + v.y * v.y + v.z * v.z + v.w * v.w;
    s  = block_sum(s);
    s2 = block_sum(s2);
    const float mean = s * (1.0f / DMODEL);
    const float var  = s2 * (1.0f / DMODEL) - mean * mean;
    const float rs   = rsqrtf(var + 1e-5f);
    float4 wv = *(const float4*)&lw[i];
    float4 bv = *(const float4*)&lb[i];
    s16x4 ov;
    ov[0] = f2bf((v.x - mean) * rs * wv.x + bv.x);
    ov[1] = f2bf((v.y - mean) * rs * wv.y + bv.y);
    ov[2] = f2bf((v.z - mean) * rs * wv.z + bv.z);
    ov[3] = f2bf((v.w - mean) * rs * wv.w + bv.w);
    *(s16x4*)&o[base + i] = ov;
}

// ---------------------------------------------------------------------------
// transpose-convert core (64x64 tile) — weight conversion only
template<typename T>
DEV_INLINE void tcvt_body(const T* sp, short* dp, int lds_, int ldd,
                          int bx, int by, short (*ls)[68], int t)
{
    const int tr0 = by * 64, tc0 = bx * 64;
    const int rr = t >> 4, cc = (t & 15) * 4;
    #pragma unroll
    for (int q = 0; q < 4; ++q) {
        const int r = q * 16 + rr;
        if constexpr (sizeof(T) == 4) {
            float4 v = *(const float4*)&sp[(long long)(tr0 + r) * lds_ + tc0 + cc];
            ls[cc + 0][r] = f2bf(v.x); ls[cc + 1][r] = f2bf(v.y);
            ls[cc + 2][r] = f2bf(v.z); ls[cc + 3][r] = f2bf(v.w);
        } else {
            s16x4 v = *(const s16x4*)&sp[(long long)(tr0 + r) * lds_ + tc0 + cc];
            ls[cc + 0][r] = v[0]; ls[cc + 1][r] = v[1];
            ls[cc + 2][r] = v[2]; ls[cc + 3][r] = v[3];
        }
    }
    __syncthreads();
    #pragma unroll
    for (int q = 0; q < 4; ++q) {
        const int c = q * 16 + rr;
        s16x4 v;
        v[0] = ls[c][cc]; v[1] = ls[c][cc + 1]; v[2] = ls[c][cc + 2]; v[3] = ls[c][cc + 3];
        *(s16x4*)&dp[(long long)(tc0 + c) * ldd + tr0 + cc] = v;
    }
}

template<typename T>
__global__ __launch_bounds__(256) void tcvt_k(
    const T* __restrict__ src, short* __restrict__ dst,
    int lds_, int ldd, int Hdiv,
    long long sSb, long long sSh, long long sDb, long long sDh)
{
    __shared__ short ls[64][68];
    const int z = blockIdx.z, zb = z / Hdiv, zh = z - zb * Hdiv;
    tcvt_body<T>(src + zb * sSb + zh * sSh, dst + zb * sDb + zh * sDh,
                 lds_, ldd, blockIdx.x, blockIdx.y, ls, threadIdx.x);
}

// merged per-layer weight convert (!big path): 3072 blocks
__global__ __launch_bounds__(256) void wcvt_k(
    const float* __restrict__ qw, const float* __restrict__ ow,
    const float* __restrict__ f1, const float* __restrict__ f2,
    short* __restrict__ wq, short* __restrict__ wo,
    short* __restrict__ w1, short* __restrict__ w2)
{
    __shared__ short ls[64][68];
    const int id = blockIdx.x;
    const float* src; short* dst; int lds_, ldd, bx, by;
    if (id < 768)       { src = qw; dst = wq; lds_ = 3072; ldd = 1024; bx = id % 48;  by = id / 48; }
    else if (id < 1024) { int i = id - 768;  src = ow; dst = wo; lds_ = 1024; ldd = 1024; bx = i % 16; by = i / 16; }
    else if (id < 2048) { int i = id - 1024; src = f1; dst = w1; lds_ = 4096; ldd = 1024; bx = i % 64; by = i / 64; }
    else                { int i = id - 2048; src = f2; dst = w2; lds_ = 1024; ldd = 4096; bx = i % 16; by = i / 16; }
    tcvt_body<float>(src, dst, lds_, ldd, bx, by, ls, threadIdx.x);
}

// plain fp32 -> bf16 convert (n4 = count/4)
__global__ __launch_bounds__(256) void cvt_k(
    const float* __restrict__ s, short* __restrict__ d, int n4)
{
    int i = blockIdx.x * 256 + threadIdx.x;
    const int stride = gridDim.x * 256;
    for (; i < n4; i += stride) {
        float4 v = *(const float4*)&s[(long long)i * 4];
        s16x4 o = { f2bf(v.x), f2bf(v.y), f2bf(v.z), f2bf(v.w) };
        *(s16x4*)&d[(long long)i * 4] = o;
    }
}

// ---------------------------------------------------------------------------
extern "C" void kernel_launch(void* const* d_in, const int* in_sizes, int n_in,
                              void* d_out, int out_size, void* d_ws, size_t ws_size,
                              hipStream_t stream)
{
    const int*   ids  = (const int*)  d_in[0];
    const float* tok  = (const float*)d_in[1];
    const float* pos  = (const float*)d_in[2];
    const float* ln1w = (const float*)d_in[3];
    const float* ln1b = (const float*)d_in[4];
    const float* qkvw = (const float*)d_in[5];
    const float* outw = (const float*)d_in[6];
    const float* outb = (const float*)d_in[7];
    const float* ln2w = (const float*)d_in[8];
    const float* ln2b = (const float*)d_in[9];
    const float* fc1w = (const float*)d_in[10];
    const float* fc1b = (const float*)d_in[11];
    const float* fc2w = (const float*)d_in[12];
    const float* fc2b = (const float*)d_in[13];
    const float* lnfw = (const float*)d_in[14];
    const float* lnfb = (const float*)d_in[15];
    float* out = (float*)d_out;

    char* ws = (char*)d_ws;
    const size_t MB = 1024 * 1024;
    float* x    = (float*)(ws);             //  0-8   f32 residual
    short* hb   = (short*)(ws + 8  * MB);   //  8-12  bf16 [2048][1024]
    short* qkvb = (short*)(ws + 12 * MB);   // 12-24  bf16 [2048][3072] (V unused)
    short* g    = (short*)(ws + 24 * MB);   // 24-40  bf16 [2048][4096]
    short* Vt   = (short*)(ws + 40 * MB);   // 40-44  bf16 [32][64][1024]
    short* fp   = (short*)(ws + 44 * MB);   // 44-60  bf16 [4][2048][1024] partials
    short* tokb = (short*)(ws + 12 * MB);   // lm_head phase only (aliases dead bufs)

    const bool big = ws_size >= (size_t)272 * MB;
    short* wq = (short*)(ws + 80 * MB);
    short *wo, *w1, *w2;
    if (big) {
        wo = (short*)(ws + 128 * MB);
        w1 = (short*)(ws + 144 * MB);
        w2 = (short*)(ws + 208 * MB);       // ends 272
    } else {
        wo = (short*)(ws + 86 * MB);
        w1 = (short*)(ws + 88 * MB);
        w2 = (short*)(ws + 96 * MB);        // ends 104
    }

    const long long LWQ = 3072LL * 1024, LWO = 1024LL * 1024;
    const long long LW1 = 4096LL * 1024, LW2 = 1024LL * 4096;
    const long long MD  = (long long)MTOK * DMODEL;

    hipFuncSetAttribute((const void*)gemm256_k,
                        hipFuncAttributeMaxDynamicSharedMemorySize, 131072);

    dim3 blk(256);
    embedln_k<<<MTOK, blk, 0, stream>>>(ids, tok, pos, x, ln1w, ln1b, hb);

    if (big) {
        tcvt_k<float><<<dim3(48, 16, 8), blk, 0, stream>>>(qkvw, wq, 3072, 1024, 1, LWQ, 0, LWQ, 0);
        tcvt_k<float><<<dim3(16, 16, 8), blk, 0, stream>>>(outw, wo, 1024, 1024, 1, LWO, 0, LWO, 0);
        tcvt_k<float><<<dim3(64, 16, 8), blk, 0, stream>>>(fc1w, w1, 4096, 1024, 1, LW1, 0, LW1, 0);
        tcvt_k<float><<<dim3(16, 64, 8), blk, 0, stream>>>(fc2w, w2, 1024, 4096, 1, LW2, 0, LW2, 0);
    }

    for (int l = 0; l < NLAYER; ++l) {
        short* wql = wq + (big ? l * LWQ : 0);
        short* wol = wo + (big ? l * LWO : 0);
        short* w1l = w1 + (big ? l * LW1 : 0);
        short* w2l = w2 + (big ? l * LW2 : 0);
        if (!big)
            wcvt_k<<<3072, blk, 0, stream>>>(
                qkvw + l * LWQ, outw + l * LWO, fc1w + l * LW1, fc2w + l * LW2,
                wql, wol, w1l, w2l);

        // qkv = ln1 @ Wqkv -> Q,K to qkvb; V transposed to Vt (EPI=4)
        gemm_k<128, 4><<<dim3(24, 16, 1), blk, 0, stream>>>(
            hb, wql, qkvb, nullptr, Vt,
            MTOK, 3 * DMODEL, DMODEL, DMODEL, DMODEL, 3 * DMODEL,
            0, 0, 0, 1.0f, 1);

        // fused attention -> hb (bf16)
        flash_k<<<dim3(8, BBATCH * NHEAD), blk, 0, stream>>>(qkvb, Vt, hb);

        // out-proj split-K=2 -> bf16 partials; x += sum + bias, hb = LN2(x)
        gemm_k<128, 5><<<dim3(8, 16, 2), blk, 0, stream>>>(
            hb, wol, fp, nullptr, nullptr,
            MTOK, DMODEL, 512, DMODEL, DMODEL, DMODEL,
            512, 512, MD, 1.0f, 1);
        fredln_k<2><<<MTOK / 4, blk, 0, stream>>>(
            fp, MD, outb + l * DMODEL, x,
            ln2w + l * DMODEL, ln2b + l * DMODEL, hb);

        // g = gelu(ln2 @ Wfc1 + b) -> bf16
        gemm_k<128, 3><<<dim3(32, 16, 1), blk, 0, stream>>>(
            hb, w1l, g, fc1b + (long long)l * 4 * DMODEL, nullptr,
            MTOK, 4 * DMODEL, DMODEL, DMODEL, DMODEL, 4 * DMODEL,
            0, 0, 0, 1.0f, 1);

        // fc2 split-K=4 -> bf16 partials; x += sum + bias, hb = next LN
        gemm_k<128, 5><<<dim3(8, 16, 4), blk, 0, stream>>>(
            g, w2l, fp, nullptr, nullptr,
            MTOK, DMODEL, 1024, 4 * DMODEL, 4 * DMODEL, DMODEL,
            1024, 1024, MD, 1.0f, 1);
        const float* nlw = (l < 7) ? ln1w + (l + 1) * DMODEL : lnfw;
        const float* nlb = (l < 7) ? ln1b + (l + 1) * DMODEL : lnfb;
        fredln_k<4><<<MTOK / 4, blk, 0, stream>>>(
            fp, MD, fc2b + l * DMODEL, x, nlw, nlb, hb);
    }

    // tok_emb -> bf16 (tokb aliases dead activation buffers)
    cvt_k<<<2048, blk, 0, stream>>>(tok, tokb, NVOCAB * DMODEL / 4);

    // logits = lnf @ tok_emb^T via 256x256 8-phase kernel (grid = 125*8)
    gemm256_k<<<dim3((NVOCAB / 256) * (MTOK / 256)), dim3(512), 131072, stream>>>(
        hb, tokb, out, DMODEL, DMODEL, DMODEL, NVOCAB, NVOCAB / 256);
}